// Round 15
// baseline (227.594 us; speedup 1.0000x reference)
//
#include <hip/hip_runtime.h>
#include <cstdint>

#define BN_EPS 1e-5f

typedef unsigned int uint;
typedef int v4i __attribute__((ext_vector_type(4)));
typedef int v16i __attribute__((ext_vector_type(16)));
typedef short v4h __attribute__((ext_vector_type(4)));

// ---------------------------------------------------------------------------
// MFMA i8 implicit GEMM v7.
// r14: kConv2P 82us @ 34% MfmaUtil; co-bottleneck = L2 weight traffic
// (0.5KB/mfma, 1.03GB) overlapping poorly at 2.8 waves/SIMD. r13 lesson:
// nB=4 with nA=2 doubles acc AGPRs -> occupancy cliff. v7: nA=1 x nB=4
// (4-row tiles): 4 mfmas per 1KB weight-fragment load (0.25KB/mfma),
// acc stays 64 regs. Wave owns 32 oc; block = 128 oc x 112 px.
// Weight traffic halves (516MB); grids stay 1792. XCD mapping exact:
// conv1 xcd=ocH, conv2 xcd=g*2+ocH -> each XCD's 288KB slice L2-resident.
//   A1i [b][784 px][256 ic] i8 +/-1;  A2i [b][784 px][1024 oc] i8 {0,1}
//   Wf  [ocb][tap][kk][lane][16B]: mfma A-fragment order. C layout
//   (verified r9-r14): col=lane&31 -> px, row=(q&3)+8*(q>>2)+4*(lane>>5).
//   P16 [g*NBc+bl][784 px][256 c] i16 raw dots, BN deferred to kRed.
//   LDS act tiles [6 rows][30 cols][256 ic], XOR swizzle ch^=((col&15)<<4).
// NOTE (r5): __launch_bounds__ 2nd arg is waves/SIMD on CDNA; never set it.
// ---------------------------------------------------------------------------

#define RSTR 7680          // 30 cols * 256 B
#define TILE6 46080        // 6 rows (4-row output tiles)

__global__ __launch_bounds__(256) void kPrep(
    const float* __restrict__ s1, const float* __restrict__ b1,
    const float* __restrict__ m1, const float* __restrict__ v1,
    const float* __restrict__ s2, const float* __restrict__ b2,
    const float* __restrict__ m2, const float* __restrict__ v2,
    const float* __restrict__ lam,
    float* __restrict__ thr1, float* __restrict__ bnA2,
    float* __restrict__ bbSum) {
  int t = blockIdx.x * 256 + threadIdx.x;
  if (t >= 1024) return;
  float inv1 = s1[t] / sqrtf(v1[t] + BN_EPS);
  float bb1 = b1[t] - m1[t] * inv1;
  thr1[t] = -bb1 / inv1;  // bit = (dot > thr); inv1 >= 0
  float inv2 = s2[t] / sqrtf(v2[t] + BN_EPS);
  bnA2[t] = inv2 * lam[t >> 8];
  if (t < 256) {
    float s = 0.f;
#pragma unroll
    for (int g = 0; g < 4; g++) {
      int i = g * 256 + t;
      float iv = s2[i] / sqrtf(v2[i] + BN_EPS);
      s += (b2[i] - m2[i] * iv) * lam[g];
    }
    bbSum[t] = s;
  }
}

// x -> A1i [b][px][256] i8 +/-1 (transpose via small LDS tile)
__global__ __launch_bounds__(256) void kQ1(const float* __restrict__ x,
                                           char* __restrict__ A1i) {
  const int tid = threadIdx.x;
  const int lane = tid & 63, cb = tid >> 6;
  const int grp = blockIdx.x;  // 32 b * 49 groups of 16 px
  const int b = grp / 49, p0 = (grp % 49) * 16;
  __shared__ char t[16][256];
  const float4* src =
      (const float4*)(x + ((size_t)(b * 256 + cb * 64 + lane) * 784 + p0));
  float4 f0 = src[0], f1 = src[1], f2 = src[2], f3 = src[3];
  const int c = cb * 64 + lane;
#define Q(V, J) t[J][c] = ((V) >= 0.f) ? (char)1 : (char)-1;
  Q(f0.x, 0)  Q(f0.y, 1)  Q(f0.z, 2)  Q(f0.w, 3)
  Q(f1.x, 4)  Q(f1.y, 5)  Q(f1.z, 6)  Q(f1.w, 7)
  Q(f2.x, 8)  Q(f2.y, 9)  Q(f2.z, 10) Q(f2.w, 11)
  Q(f3.x, 12) Q(f3.y, 13) Q(f3.z, 14) Q(f3.w, 15)
#undef Q
  __syncthreads();
  const int px = tid >> 4, ch = tid & 15;
  *(v4i*)(A1i + (size_t)(b * 784 + p0 + px) * 256 + ch * 16) =
      *(const v4i*)(&t[px][ch * 16]);
}

// w [oc][256][3][3] f32 -> Wf fragment layout:
// byte (ocb, tap, kk, l, j) = sign(w[ocb*32 + (l&31)][kk*32 + (l>>5)*16 + j][tap])
__global__ __launch_bounds__(256) void kWf(const float* __restrict__ w,
                                           char* __restrict__ Wf) {
  const int oc = blockIdx.x, ic = threadIdx.x;
  const float* s = w + (size_t)(oc * 256 + ic) * 9;
  const int ocb = oc >> 5;
  const int l = (oc & 31) + ((ic >> 4) & 1) * 32;
  const int kk = ic >> 5, j = ic & 15;
  char* base = Wf + (size_t)(ocb * 72 + kk) * 1024 + l * 16 + j;
#pragma unroll
  for (int tap = 0; tap < 9; tap++)
    base[(size_t)tap * 8 * 1024] = (s[tap] >= 0.f) ? (char)1 : (char)-1;
}

// ---------------- conv1 MFMA: 1792 blocks, 256 thr, 4-row tiles ------------
// wave w = 32-oc slice (nA=1); nB=4 px-subtiles (128 px, 112 valid).
// xcd = ocH: each XCD's 288KB weight slice stays L2-resident.
__global__ __launch_bounds__(256) void kConv1M(
    const char* __restrict__ A1i, const char* __restrict__ Wf1,
    const float* __restrict__ thr1, char* __restrict__ A2i) {
  const int tid = threadIdx.x;
  const int l = tid & 63, w = tid >> 6;
  const int xg = blockIdx.x;                  // 1792 = 8 xcd * 224
  const int ocH = xg & 7, s = xg >> 3;        // s 0..223
  const int b = s / 7, yt = s % 7;
  const int y0 = yt * 4;

  __shared__ char tile[TILE6];   // act tile; epilogue: byte-tile alias
  __shared__ float thrT[128];

  for (int i = tid; i < TILE6 / 16; i += 256) ((v4i*)tile)[i] = (v4i){0,0,0,0};
  if (tid < 128) thrT[tid] = thr1[ocH * 128 + tid];
  __syncthreads();
  {
    const char* src = A1i + (size_t)b * 784 * 256;
    for (int i = tid; i < 2688; i += 256) {  // 6 rows * 28 px * 16 chunks
      int r = i / 448, jj = i - r * 448;
      int px = jj >> 4, ch = jj & 15;
      int ry = y0 - 1 + r;
      if (ry >= 0 && ry < 28) {
        v4i v = *(const v4i*)(src + (size_t)(ry * 28 + px) * 256 + ch * 16);
        int cl = px + 1;
        *(v4i*)(tile + r * RSTR + cl * 256 + ((ch * 16) ^ ((cl & 15) << 4))) = v;
      }
    }
  }
  __syncthreads();

  const int col = l & 31, krow = l >> 5;
  int cbase[4], xm[4][3];
#pragma unroll
  for (int nb = 0; nb < 4; nb++) {
    int px = nb * 32 + col;
    int pxc = (px < 112) ? px : 111;
    int yy = pxc / 28, xx = pxc - yy * 28;
    cbase[nb] = yy * RSTR + xx * 256 + krow * 16;
#pragma unroll
    for (int e = 0; e < 3; e++) xm[nb][e] = ((xx + e) & 15) << 4;
  }

  v16i acc[4];
#pragma unroll
  for (int nb = 0; nb < 4; nb++) acc[nb] = (v16i)(0);
  const char* wb = Wf1 + (size_t)(ocH * 4 + w) * 73728 + l * 16;

  for (int d = 0; d < 3; d++) {
#pragma unroll
    for (int e = 0; e < 3; e++) {
      const char* wp = wb + (size_t)(d * 3 + e) * 8192;
#pragma unroll
      for (int kk = 0; kk < 8; kk++) {
        v4i a0 = *(const v4i*)(wp + kk * 1024);
#pragma unroll
        for (int nb = 0; nb < 4; nb++) {
          int baddr = cbase[nb] + d * RSTR + e * 256 + kk * 32;
          v4i bf = *(const v4i*)(tile + (baddr ^ xm[nb][e]));
          acc[nb] = __builtin_amdgcn_mfma_i32_32x32x32_i8(a0, bf, acc[nb], 0, 0, 0);
        }
      }
    }
  }

  __syncthreads();              // all waves done reading tile
  char* bt = tile;              // alias: [128 px][256B rows] bits, swizzled
#pragma unroll
  for (int nb = 0; nb < 4; nb++) {
    int px = nb * 32 + col;
    if (px < 112) {
#pragma unroll
      for (int qg = 0; qg < 4; qg++) {
        int ocb4 = w * 32 + qg * 8 + 4 * krow;  // 4-aligned oc in slice
        float4 th = *(const float4*)&thrT[ocb4];
        uint word = 0;
        word |= ((float)acc[nb][qg * 4 + 0] > th.x) ? 0x01u : 0u;
        word |= ((float)acc[nb][qg * 4 + 1] > th.y) ? 0x100u : 0u;
        word |= ((float)acc[nb][qg * 4 + 2] > th.z) ? 0x10000u : 0u;
        word |= ((float)acc[nb][qg * 4 + 3] > th.w) ? 0x1000000u : 0u;
        *(uint*)(bt + px * 256 + (ocb4 ^ ((px & 15) << 4))) = word;
      }
    }
  }
  __syncthreads();
  {
    char* dst = A2i + (size_t)(b * 784 + y0 * 28) * 1024 + ocH * 128;
    for (int i = tid; i < 896; i += 256) {  // 112 px * 8 chunks
      int p2 = i >> 3, ch = i & 7;
      v4i v = *(const v4i*)(bt + p2 * 256 + ((ch * 16) ^ ((p2 & 15) << 4)));
      *(v4i*)(dst + (size_t)p2 * 1024 + ch * 16) = v;
    }
  }
}

// ---------------- conv2 partial MFMA: (g,ocH) per block, 4-row tiles -------
// grid 8 xcd * (NBc*7); xcd = g*2+ocH. Raw i32 dots -> i16, BN deferred.
__global__ __launch_bounds__(256) void kConv2P(
    const char* __restrict__ A2i, const char* __restrict__ Wf2,
    short* __restrict__ P16, int b0, int NBc) {
  const int tid = threadIdx.x;
  const int l = tid & 63, w = tid >> 6;
  const int xg = blockIdx.x;                // 8 xcd * (NBc * 7)
  const int xcd = xg & 7, s = xg >> 3;
  const int g = xcd >> 1, ocH = xcd & 1;
  const int bl = s / 7, yt = s % 7;
  const int b = b0 + bl;
  const int y0 = yt * 4;

  __shared__ char tile[TILE6];

  for (int i = tid; i < TILE6 / 16; i += 256) ((v4i*)tile)[i] = (v4i){0,0,0,0};
  __syncthreads();
  {
    const char* src = A2i + (size_t)b * 784 * 1024 + g * 256;
    for (int i = tid; i < 2688; i += 256) {  // 6 rows * 28 px * 16 chunks
      int r = i / 448, jj = i - r * 448;
      int px = jj >> 4, ch = jj & 15;
      int ry = y0 - 1 + r;
      if (ry >= 0 && ry < 28) {
        v4i v = *(const v4i*)(src + (size_t)(ry * 28 + px) * 1024 + ch * 16);
        int cl = px + 1;
        *(v4i*)(tile + r * RSTR + cl * 256 + ((ch * 16) ^ ((cl & 15) << 4))) = v;
      }
    }
  }
  __syncthreads();

  const int col = l & 31, krow = l >> 5;
  int cbase[4], xm[4][3];
#pragma unroll
  for (int nb = 0; nb < 4; nb++) {
    int px = nb * 32 + col;
    int pxc = (px < 112) ? px : 111;
    int yy = pxc / 28, xx = pxc - yy * 28;
    cbase[nb] = yy * RSTR + xx * 256 + krow * 16;
#pragma unroll
    for (int e = 0; e < 3; e++) xm[nb][e] = ((xx + e) & 15) << 4;
  }

  v16i acc[4];
#pragma unroll
  for (int nb = 0; nb < 4; nb++) acc[nb] = (v16i)(0);
  const char* wb = Wf2 + (size_t)(g * 8 + ocH * 4 + w) * 73728 + l * 16;

  for (int d = 0; d < 3; d++) {
#pragma unroll
    for (int e = 0; e < 3; e++) {
      const char* wp = wb + (size_t)(d * 3 + e) * 8192;
#pragma unroll
      for (int kk = 0; kk < 8; kk++) {
        v4i a0 = *(const v4i*)(wp + kk * 1024);
#pragma unroll
        for (int nb = 0; nb < 4; nb++) {
          int baddr = cbase[nb] + d * RSTR + e * 256 + kk * 32;
          v4i bf = *(const v4i*)(tile + (baddr ^ xm[nb][e]));
          acc[nb] = __builtin_amdgcn_mfma_i32_32x32x32_i8(a0, bf, acc[nb], 0, 0, 0);
        }
      }
    }
  }

  // store raw dots as i16: P16[(g*NBc+bl)][784 px][256 c], 8B packed stores
  short* base = P16 + ((size_t)((g * NBc + bl) * 784) + y0 * 28) * 256;
#pragma unroll
  for (int nb = 0; nb < 4; nb++) {
    int px = nb * 32 + col;
    if (px < 112) {
      short* pp = base + px * 256 + ocH * 128 + w * 32 + 4 * krow;
#pragma unroll
      for (int qg = 0; qg < 4; qg++) {
        v4h v = {(short)acc[nb][qg * 4 + 0], (short)acc[nb][qg * 4 + 1],
                 (short)acc[nb][qg * 4 + 2], (short)acc[nb][qg * 4 + 3]};
        *(v4h*)(pp + 8 * qg) = v;
      }
    }
  }
}

// ---------------- reducer: BN/lambda + group-sum + identity + relu ---------
// grid (28 y, NBc bl); block 256 (thread = c). LDS transpose keeps P reads
// and out writes coalesced.
__global__ __launch_bounds__(256) void kRed(
    const short* __restrict__ P16, const float* __restrict__ bnA2,
    const float* __restrict__ bbSum, const float* __restrict__ xin,
    float* __restrict__ out, int b0, int NBc) {
  const int tid = threadIdx.x;
  const int y = blockIdx.x, bl = blockIdx.y, b = b0 + bl;

  __shared__ float vals[256 * 29];

  float cf[4];
#pragma unroll
  for (int g = 0; g < 4; g++) cf[g] = bnA2[g * 256 + tid];
  const float bbs = bbSum[tid];
  const short* Pp[4];
#pragma unroll
  for (int g = 0; g < 4; g++)
    Pp[g] = P16 + ((size_t)((g * NBc + bl) * 784) + y * 28) * 256 + tid;

  for (int x = 0; x < 28; x++) {
    float v = bbs;
#pragma unroll
    for (int g = 0; g < 4; g++)
      v += cf[g] * (float)(int)Pp[g][x * 256];
    vals[tid * 29 + x] = v;
  }
  __syncthreads();

#pragma unroll
  for (int k = 0; k < 7; k++) {
    int f = tid + 256 * k;        // 0..1791 = 256 c * 7 float4
    int c = f / 7, xq = f - 7 * c;
    size_t base = ((size_t)(b * 256 + c) * 28 + y) * 28 + xq * 4;
    float4 xi = *(const float4*)(xin + base);
    float4 o;
    o.x = fmaxf(vals[c * 29 + xq * 4 + 0] + xi.x, 0.0f);
    o.y = fmaxf(vals[c * 29 + xq * 4 + 1] + xi.y, 0.0f);
    o.z = fmaxf(vals[c * 29 + xq * 4 + 2] + xi.z, 0.0f);
    o.w = fmaxf(vals[c * 29 + xq * 4 + 3] + xi.w, 0.0f);
    *(float4*)(out + base) = o;
  }
}

extern "C" void kernel_launch(void* const* d_in, const int* in_sizes, int n_in,
                              void* d_out, int out_size, void* d_ws, size_t ws_size,
                              hipStream_t stream) {
  const float* x   = (const float*)d_in[0];
  const float* w1  = (const float*)d_in[1];
  const float* s1  = (const float*)d_in[2];
  const float* b1  = (const float*)d_in[3];
  const float* m1  = (const float*)d_in[4];
  const float* v1  = (const float*)d_in[5];
  const float* w2  = (const float*)d_in[6];
  const float* s2  = (const float*)d_in[7];
  const float* b2  = (const float*)d_in[8];
  const float* m2  = (const float*)d_in[9];
  const float* v2  = (const float*)d_in[10];
  const float* lam = (const float*)d_in[11];
  float* out = (float*)d_out;

  char* ws = (char*)d_ws;
  char*  A1i   = ws + 0;                     //  6422528 B
  char*  Wf1   = ws + 6422528;               //  2359296 B
  char*  Wf2   = ws + 8781824;               //  2359296 B
  char*  A2i   = ws + 11141120;              // 25690112 B
  float* thr1  = (float*)(ws + 36831232);
  float* bnA2  = (float*)(ws + 36835328);
  float* bbSum = (float*)(ws + 36839424);
  short* P16   = (short*)(ws + 36843520);    // NBc*1.605 MB

  // single 32-batch chunk if workspace allows (P16 = 51.4 MB), else 2x16
  const size_t needFull = 36843520ull + 4ull * 32 * 784 * 256 * 2;
  const int NBc = (ws_size >= needFull) ? 32 : 16;

  kPrep<<<4, 256, 0, stream>>>(s1, b1, m1, v1, s2, b2, m2, v2, lam,
                               thr1, bnA2, bbSum);
  kQ1<<<1568, 256, 0, stream>>>(x, A1i);
  kWf<<<1024, 256, 0, stream>>>(w1, Wf1);
  kWf<<<1024, 256, 0, stream>>>(w2, Wf2);
  kConv1M<<<1792, 256, 0, stream>>>(A1i, Wf1, thr1, A2i);
  for (int b0 = 0; b0 < 32; b0 += NBc) {
    kConv2P<<<8 * NBc * 7, 256, 0, stream>>>(A2i, Wf2, P16, b0, NBc);
    kRed<<<dim3(28, NBc), 256, 0, stream>>>(P16, bnA2, bbSum, x, out, b0, NBc);
  }
}

// Round 16
// 192.952 us; speedup vs baseline: 1.1795x; 1.1795x over previous
//
#include <hip/hip_runtime.h>
#include <cstdint>

#define BN_EPS 1e-5f

typedef unsigned int uint;
typedef int v4i __attribute__((ext_vector_type(4)));
typedef int v16i __attribute__((ext_vector_type(16)));
typedef short v4h __attribute__((ext_vector_type(4)));

// ---------------------------------------------------------------------------
// MFMA i8 implicit GEMM v8 = r14 champion config + K-loop full unroll +
// halo-only LDS init (one barrier).
// Measured family optimum (r12-r15): 2-row tiles, nA=2 x nB=2, VGPR~60:
//   r13 nA=2xnB=4: acc 128 regs -> occupancy cliff (115us)
//   r15 nA=1xnB=4: B-reads 1/mfma + TILE6 -> LDS-bound (111us)
//   r14 nA=2xnB=2: A 0.5KB/mfma AND B 0.5 reads/mfma balanced (82us)
//   A1i [b][784 px][256 ic] i8 +/-1;  A2i [b][784 px][1024 oc] i8 {0,1}
//   Wf  [ocb][tap][kk][lane][16B]: mfma A-fragment order. C layout
//   (verified r9-r15): col=lane&31 -> px, row=(q&3)+8*(q>>2)+4*(lane>>5).
//   P16 [g*NBc+bl][784 px][256 c] i16 raw dots, BN deferred to kRed.
//   LDS act tiles [4 rows][30 cols][256 ic], XOR swizzle ch^=((col&15)<<4).
// NOTE (r5): __launch_bounds__ 2nd arg is waves/SIMD on CDNA; never set it.
// ---------------------------------------------------------------------------

#define RSTR 7680          // 30 cols * 256 B
#define TILE4 30720        // 4 rows (2-row output tiles)

__global__ __launch_bounds__(256) void kPrep(
    const float* __restrict__ s1, const float* __restrict__ b1,
    const float* __restrict__ m1, const float* __restrict__ v1,
    const float* __restrict__ s2, const float* __restrict__ b2,
    const float* __restrict__ m2, const float* __restrict__ v2,
    const float* __restrict__ lam,
    float* __restrict__ thr1, float* __restrict__ bnA2,
    float* __restrict__ bbSum) {
  int t = blockIdx.x * 256 + threadIdx.x;
  if (t >= 1024) return;
  float inv1 = s1[t] / sqrtf(v1[t] + BN_EPS);
  float bb1 = b1[t] - m1[t] * inv1;
  thr1[t] = -bb1 / inv1;  // bit = (dot > thr); inv1 >= 0
  float inv2 = s2[t] / sqrtf(v2[t] + BN_EPS);
  bnA2[t] = inv2 * lam[t >> 8];
  if (t < 256) {
    float s = 0.f;
#pragma unroll
    for (int g = 0; g < 4; g++) {
      int i = g * 256 + t;
      float iv = s2[i] / sqrtf(v2[i] + BN_EPS);
      s += (b2[i] - m2[i] * iv) * lam[g];
    }
    bbSum[t] = s;
  }
}

// x -> A1i [b][px][256] i8 +/-1 (transpose via small LDS tile)
__global__ __launch_bounds__(256) void kQ1(const float* __restrict__ x,
                                           char* __restrict__ A1i) {
  const int tid = threadIdx.x;
  const int lane = tid & 63, cb = tid >> 6;
  const int grp = blockIdx.x;  // 32 b * 49 groups of 16 px
  const int b = grp / 49, p0 = (grp % 49) * 16;
  __shared__ char t[16][256];
  const float4* src =
      (const float4*)(x + ((size_t)(b * 256 + cb * 64 + lane) * 784 + p0));
  float4 f0 = src[0], f1 = src[1], f2 = src[2], f3 = src[3];
  const int c = cb * 64 + lane;
#define Q(V, J) t[J][c] = ((V) >= 0.f) ? (char)1 : (char)-1;
  Q(f0.x, 0)  Q(f0.y, 1)  Q(f0.z, 2)  Q(f0.w, 3)
  Q(f1.x, 4)  Q(f1.y, 5)  Q(f1.z, 6)  Q(f1.w, 7)
  Q(f2.x, 8)  Q(f2.y, 9)  Q(f2.z, 10) Q(f2.w, 11)
  Q(f3.x, 12) Q(f3.y, 13) Q(f3.z, 14) Q(f3.w, 15)
#undef Q
  __syncthreads();
  const int px = tid >> 4, ch = tid & 15;
  *(v4i*)(A1i + (size_t)(b * 784 + p0 + px) * 256 + ch * 16) =
      *(const v4i*)(&t[px][ch * 16]);
}

// w [oc][256][3][3] f32 -> Wf fragment layout:
// byte (ocb, tap, kk, l, j) = sign(w[ocb*32 + (l&31)][kk*32 + (l>>5)*16 + j][tap])
__global__ __launch_bounds__(256) void kWf(const float* __restrict__ w,
                                           char* __restrict__ Wf) {
  const int oc = blockIdx.x, ic = threadIdx.x;
  const float* s = w + (size_t)(oc * 256 + ic) * 9;
  const int ocb = oc >> 5;
  const int l = (oc & 31) + ((ic >> 4) & 1) * 32;
  const int kk = ic >> 5, j = ic & 15;
  char* base = Wf + (size_t)(ocb * 72 + kk) * 1024 + l * 16 + j;
#pragma unroll
  for (int tap = 0; tap < 9; tap++)
    base[(size_t)tap * 8 * 1024] = (s[tap] >= 0.f) ? (char)1 : (char)-1;
}

// ---------------- conv1 MFMA: 1792 blocks, 256 thr, 2-row tiles ------------
// wave w = 64-oc slice (nA=2 x 32); nB=2 px-subtiles (64 px, 56 valid).
__global__ __launch_bounds__(256) void kConv1M(
    const char* __restrict__ A1i, const char* __restrict__ Wf1,
    const float* __restrict__ thr1, char* __restrict__ A2i) {
  const int tid = threadIdx.x;
  const int l = tid & 63, w = tid >> 6;
  // 1792 = 8 xcd * 224; same-b blocks share an XCD (acts + Wf1 in its L2)
  const int xg = blockIdx.x;
  const int xcd = xg & 7, s = xg >> 3;        // s 0..223
  const int b = xcd * 4 + (s & 3);
  const int rest = s >> 2;                    // 0..55
  const int ocq = rest & 3, yt = rest >> 2;   // yt 0..13
  const int y0 = yt * 2;

  __shared__ char tile[TILE4];   // act tile; epilogue: byte-tile alias
  __shared__ float thrT[256];

  thrT[tid] = thr1[ocq * 256 + tid];
  {
    const v4i z = (v4i){0, 0, 0, 0};
    // halo init only: pad cols 0/29 (all rows) + out-of-range rows
    if (tid < 128) {
      int r = tid >> 5, j = tid & 31;
      int cl = (j & 1) ? 29 : 0, ch = j >> 1;
      *(v4i*)(tile + r * RSTR + cl * 256 + ((ch * 16) ^ ((cl & 15) << 4))) = z;
    }
#pragma unroll
    for (int r = 0; r < 4; r++) {
      int ry = y0 - 1 + r;
      if (ry < 0 || ry >= 28) {  // block-uniform
        for (int i = tid; i < 448; i += 256) {
          int cl = (i >> 4) + 1, ch = i & 15;
          *(v4i*)(tile + r * RSTR + cl * 256 + ((ch * 16) ^ ((cl & 15) << 4))) = z;
        }
      }
    }
    const char* src = A1i + (size_t)b * 784 * 256;
    for (int i = tid; i < 1792; i += 256) {  // 4 rows * 28 px * 16 chunks
      int r = i / 448, jj = i - r * 448;
      int px = jj >> 4, ch = jj & 15;
      int ry = y0 - 1 + r;
      if (ry >= 0 && ry < 28) {
        v4i v = *(const v4i*)(src + (size_t)(ry * 28 + px) * 256 + ch * 16);
        int cl = px + 1;
        *(v4i*)(tile + r * RSTR + cl * 256 + ((ch * 16) ^ ((cl & 15) << 4))) = v;
      }
    }
  }
  __syncthreads();

  const int col = l & 31, krow = l >> 5;
  int cbase[2], xm[2][3];
#pragma unroll
  for (int nb = 0; nb < 2; nb++) {
    int px = nb * 32 + col;
    int pxc = (px < 56) ? px : 55;
    int yy = pxc / 28, xx = pxc - yy * 28;
    cbase[nb] = yy * RSTR + xx * 256 + krow * 16;
#pragma unroll
    for (int e = 0; e < 3; e++) xm[nb][e] = ((xx + e) & 15) << 4;
  }

  v16i acc[2][2];
#pragma unroll
  for (int na = 0; na < 2; na++)
#pragma unroll
    for (int nb = 0; nb < 2; nb++) acc[na][nb] = (v16i)(0);
  const char* wb = Wf1 + (size_t)(ocq * 8 + w * 2) * 73728 + l * 16;

#pragma unroll
  for (int d = 0; d < 3; d++) {
#pragma unroll
    for (int e = 0; e < 3; e++) {
      const char* wp = wb + (size_t)(d * 3 + e) * 8192;
#pragma unroll
      for (int kk = 0; kk < 8; kk++) {
        v4i a0 = *(const v4i*)(wp + kk * 1024);
        v4i a1 = *(const v4i*)(wp + 73728 + kk * 1024);
#pragma unroll
        for (int nb = 0; nb < 2; nb++) {
          int baddr = cbase[nb] + d * RSTR + e * 256 + kk * 32;
          v4i bf = *(const v4i*)(tile + (baddr ^ xm[nb][e]));
          acc[0][nb] = __builtin_amdgcn_mfma_i32_32x32x32_i8(a0, bf, acc[0][nb], 0, 0, 0);
          acc[1][nb] = __builtin_amdgcn_mfma_i32_32x32x32_i8(a1, bf, acc[1][nb], 0, 0, 0);
        }
      }
    }
  }

  __syncthreads();              // all waves done reading tile
  char* bt = tile;              // alias: [64 px][256 oc] bytes, swizzled
#pragma unroll
  for (int na = 0; na < 2; na++) {
#pragma unroll
    for (int nb = 0; nb < 2; nb++) {
      int px = nb * 32 + col;
      if (px < 56) {
#pragma unroll
        for (int qg = 0; qg < 4; qg++) {
          int ocb4 = w * 64 + na * 32 + qg * 8 + 4 * krow;  // 4-aligned oc base
          float4 th = *(const float4*)&thrT[ocb4];
          uint word = 0;
          word |= ((float)acc[na][nb][qg * 4 + 0] > th.x) ? 0x01u : 0u;
          word |= ((float)acc[na][nb][qg * 4 + 1] > th.y) ? 0x100u : 0u;
          word |= ((float)acc[na][nb][qg * 4 + 2] > th.z) ? 0x10000u : 0u;
          word |= ((float)acc[na][nb][qg * 4 + 3] > th.w) ? 0x1000000u : 0u;
          *(uint*)(bt + px * 256 + (ocb4 ^ ((px & 15) << 4))) = word;
        }
      }
    }
  }
  __syncthreads();
  {
    char* dst = A2i + (size_t)(b * 784 + y0 * 28) * 1024 + ocq * 256;
    for (int i = tid; i < 896; i += 256) {  // 56 px * 16 chunks
      int p2 = i >> 4, ch = i & 15;
      v4i v = *(const v4i*)(bt + p2 * 256 + ((ch * 16) ^ ((p2 & 15) << 4)));
      *(v4i*)(dst + (size_t)p2 * 1024 + ch * 16) = v;
    }
  }
}

// ---------------- conv2 partial MFMA: one group per block ------------------
// grid 8*(NBc/2)*14 per chunk; raw i32 dots -> i16 partials, BN deferred.
__global__ __launch_bounds__(256) void kConv2P(
    const char* __restrict__ A2i, const char* __restrict__ Wf2,
    short* __restrict__ P16, int b0, int NBc) {
  const int tid = threadIdx.x;
  const int l = tid & 63, w = tid >> 6;
  const int xg = blockIdx.x;                // 8 xcd * (NBc/2 * 14)
  const int xcd = xg & 7, s = xg >> 3;
  const int g = xcd >> 1;
  const int bl = (s / 14) * 2 + (xcd & 1);  // 0..NBc-1
  const int yt = s % 14;
  const int b = b0 + bl;
  const int y0 = yt * 2;

  __shared__ char tile[TILE4];

  {
    const v4i z = (v4i){0, 0, 0, 0};
    if (tid < 128) {
      int r = tid >> 5, j = tid & 31;
      int cl = (j & 1) ? 29 : 0, ch = j >> 1;
      *(v4i*)(tile + r * RSTR + cl * 256 + ((ch * 16) ^ ((cl & 15) << 4))) = z;
    }
#pragma unroll
    for (int r = 0; r < 4; r++) {
      int ry = y0 - 1 + r;
      if (ry < 0 || ry >= 28) {  // block-uniform
        for (int i = tid; i < 448; i += 256) {
          int cl = (i >> 4) + 1, ch = i & 15;
          *(v4i*)(tile + r * RSTR + cl * 256 + ((ch * 16) ^ ((cl & 15) << 4))) = z;
        }
      }
    }
    const char* src = A2i + (size_t)b * 784 * 1024 + g * 256;
    for (int i = tid; i < 1792; i += 256) {  // 4 rows * 28 px * 16 chunks
      int r = i / 448, jj = i - r * 448;
      int px = jj >> 4, ch = jj & 15;
      int ry = y0 - 1 + r;
      if (ry >= 0 && ry < 28) {
        v4i v = *(const v4i*)(src + (size_t)(ry * 28 + px) * 1024 + ch * 16);
        int cl = px + 1;
        *(v4i*)(tile + r * RSTR + cl * 256 + ((ch * 16) ^ ((cl & 15) << 4))) = v;
      }
    }
  }
  __syncthreads();

  const int col = l & 31, krow = l >> 5;
  int cbase[2], xm[2][3];
#pragma unroll
  for (int nb = 0; nb < 2; nb++) {
    int px = nb * 32 + col;
    int pxc = (px < 56) ? px : 55;
    int yy = pxc / 28, xx = pxc - yy * 28;
    cbase[nb] = yy * RSTR + xx * 256 + krow * 16;
#pragma unroll
    for (int e = 0; e < 3; e++) xm[nb][e] = ((xx + e) & 15) << 4;
  }

  v16i acc[2][2];
#pragma unroll
  for (int na = 0; na < 2; na++)
#pragma unroll
    for (int nb = 0; nb < 2; nb++) acc[na][nb] = (v16i)(0);
  const char* wb = Wf2 + (size_t)(g * 8 + w * 2) * 73728 + l * 16;

#pragma unroll
  for (int d = 0; d < 3; d++) {
#pragma unroll
    for (int e = 0; e < 3; e++) {
      const char* wp = wb + (size_t)(d * 3 + e) * 8192;
#pragma unroll
      for (int kk = 0; kk < 8; kk++) {
        v4i a0 = *(const v4i*)(wp + kk * 1024);
        v4i a1 = *(const v4i*)(wp + 73728 + kk * 1024);
#pragma unroll
        for (int nb = 0; nb < 2; nb++) {
          int baddr = cbase[nb] + d * RSTR + e * 256 + kk * 32;
          v4i bf = *(const v4i*)(tile + (baddr ^ xm[nb][e]));
          acc[0][nb] = __builtin_amdgcn_mfma_i32_32x32x32_i8(a0, bf, acc[0][nb], 0, 0, 0);
          acc[1][nb] = __builtin_amdgcn_mfma_i32_32x32x32_i8(a1, bf, acc[1][nb], 0, 0, 0);
        }
      }
    }
  }

  // store raw dots as i16: P16[(g*NBc+bl)][784 px][256 c], 8B packed stores
  short* base = P16 + ((size_t)((g * NBc + bl) * 784) + y0 * 28) * 256;
#pragma unroll
  for (int na = 0; na < 2; na++) {
#pragma unroll
    for (int nb = 0; nb < 2; nb++) {
      int px = nb * 32 + col;
      if (px < 56) {
        short* pp = base + px * 256 + w * 64 + na * 32 + 4 * krow;
#pragma unroll
        for (int qg = 0; qg < 4; qg++) {
          v4h v = {(short)acc[na][nb][qg * 4 + 0], (short)acc[na][nb][qg * 4 + 1],
                   (short)acc[na][nb][qg * 4 + 2], (short)acc[na][nb][qg * 4 + 3]};
          *(v4h*)(pp + 8 * qg) = v;
        }
      }
    }
  }
}

// ---------------- reducer: BN/lambda + group-sum + identity + relu ---------
// grid (28 y, NBc bl); block 256 (thread = c). LDS transpose keeps P reads
// and out writes coalesced.
__global__ __launch_bounds__(256) void kRed(
    const short* __restrict__ P16, const float* __restrict__ bnA2,
    const float* __restrict__ bbSum, const float* __restrict__ xin,
    float* __restrict__ out, int b0, int NBc) {
  const int tid = threadIdx.x;
  const int y = blockIdx.x, bl = blockIdx.y, b = b0 + bl;

  __shared__ float vals[256 * 29];

  float cf[4];
#pragma unroll
  for (int g = 0; g < 4; g++) cf[g] = bnA2[g * 256 + tid];
  const float bbs = bbSum[tid];
  const short* Pp[4];
#pragma unroll
  for (int g = 0; g < 4; g++)
    Pp[g] = P16 + ((size_t)((g * NBc + bl) * 784) + y * 28) * 256 + tid;

  for (int x = 0; x < 28; x++) {
    float v = bbs;
#pragma unroll
    for (int g = 0; g < 4; g++)
      v += cf[g] * (float)(int)Pp[g][x * 256];
    vals[tid * 29 + x] = v;
  }
  __syncthreads();

#pragma unroll
  for (int k = 0; k < 7; k++) {
    int f = tid + 256 * k;        // 0..1791 = 256 c * 7 float4
    int c = f / 7, xq = f - 7 * c;
    size_t base = ((size_t)(b * 256 + c) * 28 + y) * 28 + xq * 4;
    float4 xi = *(const float4*)(xin + base);
    float4 o;
    o.x = fmaxf(vals[c * 29 + xq * 4 + 0] + xi.x, 0.0f);
    o.y = fmaxf(vals[c * 29 + xq * 4 + 1] + xi.y, 0.0f);
    o.z = fmaxf(vals[c * 29 + xq * 4 + 2] + xi.z, 0.0f);
    o.w = fmaxf(vals[c * 29 + xq * 4 + 3] + xi.w, 0.0f);
    *(float4*)(out + base) = o;
  }
}

extern "C" void kernel_launch(void* const* d_in, const int* in_sizes, int n_in,
                              void* d_out, int out_size, void* d_ws, size_t ws_size,
                              hipStream_t stream) {
  const float* x   = (const float*)d_in[0];
  const float* w1  = (const float*)d_in[1];
  const float* s1  = (const float*)d_in[2];
  const float* b1  = (const float*)d_in[3];
  const float* m1  = (const float*)d_in[4];
  const float* v1  = (const float*)d_in[5];
  const float* w2  = (const float*)d_in[6];
  const float* s2  = (const float*)d_in[7];
  const float* b2  = (const float*)d_in[8];
  const float* m2  = (const float*)d_in[9];
  const float* v2  = (const float*)d_in[10];
  const float* lam = (const float*)d_in[11];
  float* out = (float*)d_out;

  char* ws = (char*)d_ws;
  char*  A1i   = ws + 0;                     //  6422528 B
  char*  Wf1   = ws + 6422528;               //  2359296 B
  char*  Wf2   = ws + 8781824;               //  2359296 B
  char*  A2i   = ws + 11141120;              // 25690112 B
  float* thr1  = (float*)(ws + 36831232);
  float* bnA2  = (float*)(ws + 36835328);
  float* bbSum = (float*)(ws + 36839424);
  short* P16   = (short*)(ws + 36843520);    // NBc*1.605 MB

  // single 32-batch chunk if workspace allows (P16 = 51.4 MB), else 2x16
  const size_t needFull = 36843520ull + 4ull * 32 * 784 * 256 * 2;
  const int NBc = (ws_size >= needFull) ? 32 : 16;

  kPrep<<<4, 256, 0, stream>>>(s1, b1, m1, v1, s2, b2, m2, v2, lam,
                               thr1, bnA2, bbSum);
  kQ1<<<1568, 256, 0, stream>>>(x, A1i);
  kWf<<<1024, 256, 0, stream>>>(w1, Wf1);
  kWf<<<1024, 256, 0, stream>>>(w2, Wf2);
  kConv1M<<<1792, 256, 0, stream>>>(A1i, Wf1, thr1, A2i);
  for (int b0 = 0; b0 < 32; b0 += NBc) {
    kConv2P<<<8 * (NBc / 2) * 14, 256, 0, stream>>>(A2i, Wf2, P16, b0, NBc);
    kRed<<<dim3(28, NBc), 256, 0, stream>>>(P16, bnA2, bbSum, x, out, b0, NBc);
  }
}

// Round 17
// 185.412 us; speedup vs baseline: 1.2275x; 1.0407x over previous
//
#include <hip/hip_runtime.h>
#include <cstdint>

#define BN_EPS 1e-5f

typedef unsigned int uint;
typedef int v4i __attribute__((ext_vector_type(4)));
typedef int v16i __attribute__((ext_vector_type(16)));
typedef short v4h __attribute__((ext_vector_type(4)));

// ---------------------------------------------------------------------------
// MFMA i8 implicit GEMM v9.
// r16: full unroll neutral -> latency plateau at 35% occupancy, 34% MfmaUtil.
// v9: keep the measured per-wave optimum (nA=2 x nB=2, acc 64 AGPR, r14),
// but 8-wave blocks (512 thr) = 4 oc-slices x 2 px-halves on 4-row tiles:
// staging bytes/px -25%, half the blocks/barriers, occupancy can reach the
// 16 waves/CU register-tier cap (124 regs < 128).
//   A1i [b][784 px][256 ic] i8 +/-1;  A2i [b][784 px][1024 oc] i8 {0,1}
//   Wf  [ocb][tap][kk][lane][16B]: mfma A-fragment order. C layout
//   (verified r9-r16): col=lane&31 -> px, row=(q&3)+8*(q>>2)+4*(lane>>5).
//   P16 [g*NBc+bl][784 px][256 c] i16 raw dots, BN deferred to kRed.
//   LDS act tiles [6 rows][30 cols][256 ic], XOR swizzle ch^=((col&15)<<4).
// NOTE (r5): __launch_bounds__ 2nd arg is waves/SIMD on CDNA; never set it.
// ---------------------------------------------------------------------------

#define RSTR 7680          // 30 cols * 256 B
#define TILE6 46080        // 6 rows (4-row output tiles)

__global__ __launch_bounds__(256) void kPrep(
    const float* __restrict__ s1, const float* __restrict__ b1,
    const float* __restrict__ m1, const float* __restrict__ v1,
    const float* __restrict__ s2, const float* __restrict__ b2,
    const float* __restrict__ m2, const float* __restrict__ v2,
    const float* __restrict__ lam,
    float* __restrict__ thr1, float* __restrict__ bnA2,
    float* __restrict__ bbSum) {
  int t = blockIdx.x * 256 + threadIdx.x;
  if (t >= 1024) return;
  float inv1 = s1[t] / sqrtf(v1[t] + BN_EPS);
  float bb1 = b1[t] - m1[t] * inv1;
  thr1[t] = -bb1 / inv1;  // bit = (dot > thr); inv1 >= 0
  float inv2 = s2[t] / sqrtf(v2[t] + BN_EPS);
  bnA2[t] = inv2 * lam[t >> 8];
  if (t < 256) {
    float s = 0.f;
#pragma unroll
    for (int g = 0; g < 4; g++) {
      int i = g * 256 + t;
      float iv = s2[i] / sqrtf(v2[i] + BN_EPS);
      s += (b2[i] - m2[i] * iv) * lam[g];
    }
    bbSum[t] = s;
  }
}

// x -> A1i [b][px][256] i8 +/-1 (transpose via small LDS tile)
__global__ __launch_bounds__(256) void kQ1(const float* __restrict__ x,
                                           char* __restrict__ A1i) {
  const int tid = threadIdx.x;
  const int lane = tid & 63, cb = tid >> 6;
  const int grp = blockIdx.x;  // 32 b * 49 groups of 16 px
  const int b = grp / 49, p0 = (grp % 49) * 16;
  __shared__ char t[16][256];
  const float4* src =
      (const float4*)(x + ((size_t)(b * 256 + cb * 64 + lane) * 784 + p0));
  float4 f0 = src[0], f1 = src[1], f2 = src[2], f3 = src[3];
  const int c = cb * 64 + lane;
#define Q(V, J) t[J][c] = ((V) >= 0.f) ? (char)1 : (char)-1;
  Q(f0.x, 0)  Q(f0.y, 1)  Q(f0.z, 2)  Q(f0.w, 3)
  Q(f1.x, 4)  Q(f1.y, 5)  Q(f1.z, 6)  Q(f1.w, 7)
  Q(f2.x, 8)  Q(f2.y, 9)  Q(f2.z, 10) Q(f2.w, 11)
  Q(f3.x, 12) Q(f3.y, 13) Q(f3.z, 14) Q(f3.w, 15)
#undef Q
  __syncthreads();
  const int px = tid >> 4, ch = tid & 15;
  *(v4i*)(A1i + (size_t)(b * 784 + p0 + px) * 256 + ch * 16) =
      *(const v4i*)(&t[px][ch * 16]);
}

// w [oc][256][3][3] f32 -> Wf fragment layout:
// byte (ocb, tap, kk, l, j) = sign(w[ocb*32 + (l&31)][kk*32 + (l>>5)*16 + j][tap])
__global__ __launch_bounds__(256) void kWf(const float* __restrict__ w,
                                           char* __restrict__ Wf) {
  const int oc = blockIdx.x, ic = threadIdx.x;
  const float* s = w + (size_t)(oc * 256 + ic) * 9;
  const int ocb = oc >> 5;
  const int l = (oc & 31) + ((ic >> 4) & 1) * 32;
  const int kk = ic >> 5, j = ic & 15;
  char* base = Wf + (size_t)(ocb * 72 + kk) * 1024 + l * 16 + j;
#pragma unroll
  for (int tap = 0; tap < 9; tap++)
    base[(size_t)tap * 8 * 1024] = (s[tap] >= 0.f) ? (char)1 : (char)-1;
}

// ---------------- conv1 MFMA: 896 blocks, 512 thr, 4-row tiles -------------
// 8 waves = 4 oc-slices x 2 px-halves; per wave nA=2 x nB=2 over its half.
__global__ __launch_bounds__(512) void kConv1M(
    const char* __restrict__ A1i, const char* __restrict__ Wf1,
    const float* __restrict__ thr1, char* __restrict__ A2i) {
  const int tid = threadIdx.x;
  const int l = tid & 63, w = tid >> 6;
  const int wslice = w & 3, ph = w >> 2;
  const int xg = blockIdx.x;                  // 896 = 8 xcd * 112
  const int xcd = xg & 7, s = xg >> 3;        // s 0..111
  const int b = xcd * 4 + (s & 3);
  const int rest = s >> 2;                    // 0..27
  const int ocq = rest & 3, yt = rest >> 2;   // yt 0..6
  const int y0 = yt * 4;

  __shared__ char tile[TILE6];   // act tile; epilogue: byte-tile alias
  __shared__ float thrT[256];

  if (tid < 256) thrT[tid] = thr1[ocq * 256 + tid];
  {
    const v4i z = (v4i){0, 0, 0, 0};
    // halo: pad cols 0/29, 6 rows x 16 ch = 192 v4i
    if (tid < 192) {
      int r = tid / 32, j = tid & 31;
      int cl = (j & 1) ? 29 : 0, ch = j >> 1;
      *(v4i*)(tile + r * RSTR + cl * 256 + ((ch * 16) ^ ((cl & 15) << 4))) = z;
    }
#pragma unroll
    for (int r = 0; r < 6; r++) {
      int ry = y0 - 1 + r;
      if (ry < 0 || ry >= 28) {  // block-uniform
        if (tid < 448) {
          int cl = (tid >> 4) + 1, ch = tid & 15;
          *(v4i*)(tile + r * RSTR + cl * 256 + ((ch * 16) ^ ((cl & 15) << 4))) = z;
        }
      }
    }
    const char* src = A1i + (size_t)b * 784 * 256;
    for (int i = tid; i < 2688; i += 512) {  // 6 rows * 28 px * 16 chunks
      int r = i / 448, jj = i - r * 448;
      int px = jj >> 4, ch = jj & 15;
      int ry = y0 - 1 + r;
      if (ry >= 0 && ry < 28) {
        v4i v = *(const v4i*)(src + (size_t)(ry * 28 + px) * 256 + ch * 16);
        int cl = px + 1;
        *(v4i*)(tile + r * RSTR + cl * 256 + ((ch * 16) ^ ((cl & 15) << 4))) = v;
      }
    }
  }
  __syncthreads();

  const int col = l & 31, krow = l >> 5;
  int cbase[2], xm[2][3];
#pragma unroll
  for (int nb = 0; nb < 2; nb++) {
    int px = ph * 64 + nb * 32 + col;
    int pxc = (px < 112) ? px : 111;
    int yy = pxc / 28, xx = pxc - yy * 28;
    cbase[nb] = yy * RSTR + xx * 256 + krow * 16;
#pragma unroll
    for (int e = 0; e < 3; e++) xm[nb][e] = ((xx + e) & 15) << 4;
  }

  v16i acc[2][2];
#pragma unroll
  for (int na = 0; na < 2; na++)
#pragma unroll
    for (int nb = 0; nb < 2; nb++) acc[na][nb] = (v16i)(0);
  const char* wb = Wf1 + (size_t)(ocq * 8 + wslice * 2) * 73728 + l * 16;

#pragma unroll
  for (int d = 0; d < 3; d++) {
#pragma unroll
    for (int e = 0; e < 3; e++) {
      const char* wp = wb + (size_t)(d * 3 + e) * 8192;
#pragma unroll
      for (int kk = 0; kk < 8; kk++) {
        v4i a0 = *(const v4i*)(wp + kk * 1024);
        v4i a1 = *(const v4i*)(wp + 73728 + kk * 1024);
#pragma unroll
        for (int nb = 0; nb < 2; nb++) {
          int baddr = cbase[nb] + d * RSTR + e * 256 + kk * 32;
          v4i bf = *(const v4i*)(tile + (baddr ^ xm[nb][e]));
          acc[0][nb] = __builtin_amdgcn_mfma_i32_32x32x32_i8(a0, bf, acc[0][nb], 0, 0, 0);
          acc[1][nb] = __builtin_amdgcn_mfma_i32_32x32x32_i8(a1, bf, acc[1][nb], 0, 0, 0);
        }
      }
    }
  }

  __syncthreads();              // all waves done reading tile
  char* bt = tile;              // alias: [128 px][256 oc] bytes, swizzled
#pragma unroll
  for (int na = 0; na < 2; na++) {
#pragma unroll
    for (int nb = 0; nb < 2; nb++) {
      int px = ph * 64 + nb * 32 + col;
      if (px < 112) {
#pragma unroll
        for (int qg = 0; qg < 4; qg++) {
          int ocb4 = wslice * 64 + na * 32 + qg * 8 + 4 * krow;
          float4 th = *(const float4*)&thrT[ocb4];
          uint word = 0;
          word |= ((float)acc[na][nb][qg * 4 + 0] > th.x) ? 0x01u : 0u;
          word |= ((float)acc[na][nb][qg * 4 + 1] > th.y) ? 0x100u : 0u;
          word |= ((float)acc[na][nb][qg * 4 + 2] > th.z) ? 0x10000u : 0u;
          word |= ((float)acc[na][nb][qg * 4 + 3] > th.w) ? 0x1000000u : 0u;
          *(uint*)(bt + px * 256 + (ocb4 ^ ((px & 15) << 4))) = word;
        }
      }
    }
  }
  __syncthreads();
  {
    char* dst = A2i + (size_t)(b * 784 + y0 * 28) * 1024 + ocq * 256;
    for (int i = tid; i < 1792; i += 512) {  // 112 px * 16 chunks
      int p2 = i >> 4, ch = i & 15;
      v4i v = *(const v4i*)(bt + p2 * 256 + ((ch * 16) ^ ((p2 & 15) << 4)));
      *(v4i*)(dst + (size_t)p2 * 1024 + ch * 16) = v;
    }
  }
}

// ---------------- conv2 partial MFMA: (g) per block, 512 thr, 4-row --------
// grid 8 xcd * (NBc/2 * 7); xcd = g*2 + (bl&1). Raw dots -> i16, BN deferred.
__global__ __launch_bounds__(512) void kConv2P(
    const char* __restrict__ A2i, const char* __restrict__ Wf2,
    short* __restrict__ P16, int b0, int NBc) {
  const int tid = threadIdx.x;
  const int l = tid & 63, w = tid >> 6;
  const int wslice = w & 3, ph = w >> 2;
  const int xg = blockIdx.x;                // 8 xcd * (NBc/2 * 7)
  const int xcd = xg & 7, s = xg >> 3;
  const int g = xcd >> 1;
  const int bl = (s / 7) * 2 + (xcd & 1);   // 0..NBc-1
  const int yt = s % 7;
  const int b = b0 + bl;
  const int y0 = yt * 4;

  __shared__ char tile[TILE6];

  {
    const v4i z = (v4i){0, 0, 0, 0};
    if (tid < 192) {
      int r = tid / 32, j = tid & 31;
      int cl = (j & 1) ? 29 : 0, ch = j >> 1;
      *(v4i*)(tile + r * RSTR + cl * 256 + ((ch * 16) ^ ((cl & 15) << 4))) = z;
    }
#pragma unroll
    for (int r = 0; r < 6; r++) {
      int ry = y0 - 1 + r;
      if (ry < 0 || ry >= 28) {  // block-uniform
        if (tid < 448) {
          int cl = (tid >> 4) + 1, ch = tid & 15;
          *(v4i*)(tile + r * RSTR + cl * 256 + ((ch * 16) ^ ((cl & 15) << 4))) = z;
        }
      }
    }
    const char* src = A2i + (size_t)b * 784 * 1024 + g * 256;
    for (int i = tid; i < 2688; i += 512) {  // 6 rows * 28 px * 16 chunks
      int r = i / 448, jj = i - r * 448;
      int px = jj >> 4, ch = jj & 15;
      int ry = y0 - 1 + r;
      if (ry >= 0 && ry < 28) {
        v4i v = *(const v4i*)(src + (size_t)(ry * 28 + px) * 1024 + ch * 16);
        int cl = px + 1;
        *(v4i*)(tile + r * RSTR + cl * 256 + ((ch * 16) ^ ((cl & 15) << 4))) = v;
      }
    }
  }
  __syncthreads();

  const int col = l & 31, krow = l >> 5;
  int cbase[2], xm[2][3];
#pragma unroll
  for (int nb = 0; nb < 2; nb++) {
    int px = ph * 64 + nb * 32 + col;
    int pxc = (px < 112) ? px : 111;
    int yy = pxc / 28, xx = pxc - yy * 28;
    cbase[nb] = yy * RSTR + xx * 256 + krow * 16;
#pragma unroll
    for (int e = 0; e < 3; e++) xm[nb][e] = ((xx + e) & 15) << 4;
  }

  v16i acc[2][2];
#pragma unroll
  for (int na = 0; na < 2; na++)
#pragma unroll
    for (int nb = 0; nb < 2; nb++) acc[na][nb] = (v16i)(0);
  const char* wb = Wf2 + (size_t)(g * 8 + wslice * 2) * 73728 + l * 16;

#pragma unroll
  for (int d = 0; d < 3; d++) {
#pragma unroll
    for (int e = 0; e < 3; e++) {
      const char* wp = wb + (size_t)(d * 3 + e) * 8192;
#pragma unroll
      for (int kk = 0; kk < 8; kk++) {
        v4i a0 = *(const v4i*)(wp + kk * 1024);
        v4i a1 = *(const v4i*)(wp + 73728 + kk * 1024);
#pragma unroll
        for (int nb = 0; nb < 2; nb++) {
          int baddr = cbase[nb] + d * RSTR + e * 256 + kk * 32;
          v4i bf = *(const v4i*)(tile + (baddr ^ xm[nb][e]));
          acc[0][nb] = __builtin_amdgcn_mfma_i32_32x32x32_i8(a0, bf, acc[0][nb], 0, 0, 0);
          acc[1][nb] = __builtin_amdgcn_mfma_i32_32x32x32_i8(a1, bf, acc[1][nb], 0, 0, 0);
        }
      }
    }
  }

  // store raw dots as i16: P16[(g*NBc+bl)][784 px][256 c], 8B packed stores
  short* base = P16 + ((size_t)((g * NBc + bl) * 784) + y0 * 28) * 256;
#pragma unroll
  for (int na = 0; na < 2; na++) {
#pragma unroll
    for (int nb = 0; nb < 2; nb++) {
      int px = ph * 64 + nb * 32 + col;
      if (px < 112) {
        short* pp = base + px * 256 + wslice * 64 + na * 32 + 4 * krow;
#pragma unroll
        for (int qg = 0; qg < 4; qg++) {
          v4h v = {(short)acc[na][nb][qg * 4 + 0], (short)acc[na][nb][qg * 4 + 1],
                   (short)acc[na][nb][qg * 4 + 2], (short)acc[na][nb][qg * 4 + 3]};
          *(v4h*)(pp + 8 * qg) = v;
        }
      }
    }
  }
}

// ---------------- reducer: BN/lambda + group-sum + identity + relu ---------
// grid (28 y, NBc bl); block 256 (thread = c). LDS transpose keeps P reads
// and out writes coalesced.
__global__ __launch_bounds__(256) void kRed(
    const short* __restrict__ P16, const float* __restrict__ bnA2,
    const float* __restrict__ bbSum, const float* __restrict__ xin,
    float* __restrict__ out, int b0, int NBc) {
  const int tid = threadIdx.x;
  const int y = blockIdx.x, bl = blockIdx.y, b = b0 + bl;

  __shared__ float vals[256 * 29];

  float cf[4];
#pragma unroll
  for (int g = 0; g < 4; g++) cf[g] = bnA2[g * 256 + tid];
  const float bbs = bbSum[tid];
  const short* Pp[4];
#pragma unroll
  for (int g = 0; g < 4; g++)
    Pp[g] = P16 + ((size_t)((g * NBc + bl) * 784) + y * 28) * 256 + tid;

  for (int x = 0; x < 28; x++) {
    float v = bbs;
#pragma unroll
    for (int g = 0; g < 4; g++)
      v += cf[g] * (float)(int)Pp[g][x * 256];
    vals[tid * 29 + x] = v;
  }
  __syncthreads();

#pragma unroll
  for (int k = 0; k < 7; k++) {
    int f = tid + 256 * k;        // 0..1791 = 256 c * 7 float4
    int c = f / 7, xq = f - 7 * c;
    size_t base = ((size_t)(b * 256 + c) * 28 + y) * 28 + xq * 4;
    float4 xi = *(const float4*)(xin + base);
    float4 o;
    o.x = fmaxf(vals[c * 29 + xq * 4 + 0] + xi.x, 0.0f);
    o.y = fmaxf(vals[c * 29 + xq * 4 + 1] + xi.y, 0.0f);
    o.z = fmaxf(vals[c * 29 + xq * 4 + 2] + xi.z, 0.0f);
    o.w = fmaxf(vals[c * 29 + xq * 4 + 3] + xi.w, 0.0f);
    *(float4*)(out + base) = o;
  }
}

extern "C" void kernel_launch(void* const* d_in, const int* in_sizes, int n_in,
                              void* d_out, int out_size, void* d_ws, size_t ws_size,
                              hipStream_t stream) {
  const float* x   = (const float*)d_in[0];
  const float* w1  = (const float*)d_in[1];
  const float* s1  = (const float*)d_in[2];
  const float* b1  = (const float*)d_in[3];
  const float* m1  = (const float*)d_in[4];
  const float* v1  = (const float*)d_in[5];
  const float* w2  = (const float*)d_in[6];
  const float* s2  = (const float*)d_in[7];
  const float* b2  = (const float*)d_in[8];
  const float* m2  = (const float*)d_in[9];
  const float* v2  = (const float*)d_in[10];
  const float* lam = (const float*)d_in[11];
  float* out = (float*)d_out;

  char* ws = (char*)d_ws;
  char*  A1i   = ws + 0;                     //  6422528 B
  char*  Wf1   = ws + 6422528;               //  2359296 B
  char*  Wf2   = ws + 8781824;               //  2359296 B
  char*  A2i   = ws + 11141120;              // 25690112 B
  float* thr1  = (float*)(ws + 36831232);
  float* bnA2  = (float*)(ws + 36835328);
  float* bbSum = (float*)(ws + 36839424);
  short* P16   = (short*)(ws + 36843520);    // NBc*1.605 MB

  // single 32-batch chunk if workspace allows (P16 = 51.4 MB), else 2x16
  const size_t needFull = 36843520ull + 4ull * 32 * 784 * 256 * 2;
  const int NBc = (ws_size >= needFull) ? 32 : 16;

  kPrep<<<4, 256, 0, stream>>>(s1, b1, m1, v1, s2, b2, m2, v2, lam,
                               thr1, bnA2, bbSum);
  kQ1<<<1568, 256, 0, stream>>>(x, A1i);
  kWf<<<1024, 256, 0, stream>>>(w1, Wf1);
  kWf<<<1024, 256, 0, stream>>>(w2, Wf2);
  kConv1M<<<896, 512, 0, stream>>>(A1i, Wf1, thr1, A2i);
  for (int b0 = 0; b0 < 32; b0 += NBc) {
    kConv2P<<<8 * (NBc / 2) * 7, 512, 0, stream>>>(A2i, Wf2, P16, b0, NBc);
    kRed<<<dim3(28, NBc), 256, 0, stream>>>(P16, bnA2, bbSum, x, out, b0, NBc);
  }
}